// Round 1
// baseline (1197.119 us; speedup 1.0000x reference)
//
#include <hip/hip_runtime.h>
#include <math.h>

typedef _Float16 f16;
typedef _Float16 f16x4 __attribute__((ext_vector_type(4)));
typedef _Float16 f16x8 __attribute__((ext_vector_type(8)));
typedef float f32x4 __attribute__((ext_vector_type(4)));

#define DEV static __device__ __forceinline__

// ---------------- workspace layout (byte offsets, all 256-aligned) ----------------
#define OFF_X16   ((size_t)0)                  // x16: 38400x768 f16
#define OFF_UX    ((size_t)58982400)           // ux16: 38400x2048 f16 ; t1 (f32 38400x512) overlays after recurrence
#define OFF_OUTS  (OFF_UX + 157286400)         // outs16: 38400x512 f16 (o-gate outputs)
#define OFF_WD    (OFF_OUTS + 39321600)        // Wd16 512x512
#define OFF_WALL  (OFF_WD + 524288)            // Wall16 2048x512
#define OFF_U16   (OFF_WALL + 2097152)         // Uall16 2048x768
#define OFF_W2    (OFF_U16 + 3145728)          // A1_W2 512x512
#define OFF_WIH   (OFF_W2 + 524288)            // L2_Wih 2048x512
#define OFF_WHH   (OFF_WIH + 2097152)          // L2_Whh 2048x512
#define OFF_A2W1  (OFF_WHH + 2097152)          // A2_W1 512x512
#define OFF_A2W2  (OFF_A2W1 + 524288)          // A2_W2 512x512
#define OFF_L3W   (OFF_A2W2 + 524288)          // lin3 256x512
#define OFF_H16   (OFF_L3W + 262144)           // h 1280x512 f16
#define OFF_C16   (OFF_H16 + 1310720)          // c 1280x512 f16
#define OFF_C32   (OFF_C16 + 1310720)          // c 1280x512 f32
#define OFF_CSL   (OFF_C32 + 2621440)          // c_s1 1280x512 f32
#define OFF_G4    (OFF_CSL + 2621440)          // gates 1280x2048 f32 ; lstm2 gates overlay
#define OFF_W1L   (OFF_G4 + 10485760)          // w1last 5x512 f32
#define OFF_L1O32 (OFF_W1L + 10240)            // lstm1_out 1280x512 f32 [b][d][h]
#define OFF_L1O16 (OFF_L1O32 + 2621440)
#define OFF_XI2   (OFF_L1O16 + 1310720)        // xi2 1280x2048 f32
#define OFF_C2    (OFF_XI2 + 10485760)         // c2 256x512 f32
#define OFF_H2    (OFF_C2 + 524288)            // h2 256x512 f16
#define OFF_L2O32 (OFF_H2 + 262144)            // lstm2_out 1280x512 f32 [b][t][h]
#define OFF_L2O16 (OFF_L2O32 + 2621440)
#define OFF_U2    (OFF_L2O16 + 1310720)        // u2 1280x512 f32
#define OFF_V2    (OFF_U2 + 2621440)           // v2 256x512 f32
#define OFF_CTX16 (OFF_V2 + 524288)            // ctx 256x512 f16
#define OFF_H3    (OFF_CTX16 + 262144)         // h3 256x256 f32
#define WS_NEED   (OFF_H3 + 262144)            // ~294 MiB

DEV float sigf(float x) { return 1.f / (1.f + __expf(-x)); }

DEV void gload16(const f16* g, f16x8* lds) {
  __builtin_amdgcn_global_load_lds((const __attribute__((address_space(1))) void*)g,
                                   (__attribute__((address_space(3))) void*)lds, 16, 0, 0);
}

// ---------------- generic 128x128 tile fp16 MFMA GEMM core ----------------
// A: MxK row-major (ld=K), Bt: NxK row-major (ld=K) i.e. weights in (out,in) layout.
// C[r][c] = sum_k A[r][k]*Bt[c][k], delivered to epi(row,col,val) in fp32.
// LDS: sh[0..2047] = A bufs, sh[2048..4095] = B bufs (f16x8 units; 64KB total).
// XOR swizzle: 16B chunk at logical (row, ch) lives at linear chunk row*8 + (ch ^ (row&7));
// staging inverts the swizzle on the global source address (global_load_lds dest must be linear).
template <class Epi>
DEV void gemm_tile(const f16* __restrict__ A, const f16* __restrict__ Bt, int K,
                   int rowBase, int colBase, f16x8* sh, Epi epi) {
  const int t = threadIdx.x;
  const int lane = t & 63;
  const int w = t >> 6;
  const int wr = (w >> 1) * 64, wc = (w & 1) * 64;
  f32x4 acc[4][4] = {};

  const f16* Arow = A + (size_t)rowBase * K;
  const f16* Brow = Bt + (size_t)colBase * K;

  auto stage = [&](f16x8* dstBase, const f16* src, int k0) {
#pragma unroll
    for (int i = 0; i < 4; ++i) {
      int c = i * 256 + t;           // chunk id within 128x8-chunk tile
      int r = c >> 3;
      int cc = (c & 7) ^ (r & 7);    // inverse swizzle on source
      gload16(src + (size_t)r * K + (k0 + cc * 8), dstBase + i * 256 + (t & 192));
    }
  };

  stage(sh, Arow, 0);
  stage(sh + 2048, Brow, 0);
  asm volatile("s_waitcnt vmcnt(0)" ::: "memory");
  __syncthreads();

  const int nk = K >> 6;
  for (int kt = 0; kt < nk; ++kt) {
    const int cur = kt & 1;
    if (kt + 1 < nk) {
      stage(sh + (cur ^ 1) * 1024, Arow, (kt + 1) * 64);
      stage(sh + 2048 + (cur ^ 1) * 1024, Brow, (kt + 1) * 64);
    }
    const f16x8* shA = sh + cur * 1024;
    const f16x8* shB = sh + 2048 + cur * 1024;
    const int rr = lane & 15;
    const int chBase = lane >> 4;
#pragma unroll
    for (int kk = 0; kk < 2; ++kk) {
      const int ch = kk * 4 + chBase;
      f16x8 af[4], bf[4];
#pragma unroll
      for (int m = 0; m < 4; ++m) { int row = wr + m * 16 + rr; af[m] = shA[row * 8 + (ch ^ (row & 7))]; }
#pragma unroll
      for (int n = 0; n < 4; ++n) { int row = wc + n * 16 + rr; bf[n] = shB[row * 8 + (ch ^ (row & 7))]; }
#pragma unroll
      for (int m = 0; m < 4; ++m)
#pragma unroll
        for (int n = 0; n < 4; ++n)
          acc[m][n] = __builtin_amdgcn_mfma_f32_16x16x32_f16(af[m], bf[n], acc[m][n], 0, 0, 0);
    }
    asm volatile("s_waitcnt vmcnt(0)" ::: "memory");
    __syncthreads();
  }

  const int er = (lane >> 4) * 4;   // C/D layout: col = lane&15, row = (lane>>4)*4 + j (verified gfx950)
  const int ec = lane & 15;
#pragma unroll
  for (int m = 0; m < 4; ++m)
#pragma unroll
    for (int n = 0; n < 4; ++n)
#pragma unroll
      for (int j = 0; j < 4; ++j)
        epi(rowBase + wr + m * 16 + er + j, colBase + wc + n * 16 + ec, acc[m][n][j]);
}

// ---------------- generic bias/act GEMM wrapper ----------------
// ACT: 0=none, 2=tanh, 3=relu
template <int ACT, bool O32, bool O16>
__global__ __launch_bounds__(256, 2) void k_gemm(const f16* __restrict__ A, const f16* __restrict__ Bt,
                                                 int K, int N, const float* bias, const float* bias2,
                                                 float* C32, f16* C16) {
  __shared__ f16x8 sh[4096];
  const int rb = blockIdx.y * 128, cb = blockIdx.x * 128;
  gemm_tile(A, Bt, K, rb, cb, sh, [&](int r, int c, float v) {
    if (bias)  v += bias[c];
    if (bias2) v += bias2[c];
    if (ACT == 2) v = tanhf(v);
    else if (ACT == 3) v = fmaxf(v, 0.f);
    if (O32) C32[(size_t)r * N + c] = v;
    if (O16) C16[(size_t)r * N + c] = (f16)v;
  });
}

// ---------------- TimeLSTM per-step: merged (h@Wall) and (c@Wd) GEMMs ----------------
__global__ __launch_bounds__(256, 2) void k_step(const f16* __restrict__ h16, const f16* __restrict__ c16,
                                                 const f16* __restrict__ Wall, const f16* __restrict__ Wd,
                                                 const f16* __restrict__ ux, const float* __restrict__ Wall_b,
                                                 const float* __restrict__ Uall_b, const float* __restrict__ Wd_b,
                                                 float* __restrict__ g4, float* __restrict__ csl, int s) {
  __shared__ f16x8 sh[4096];
  const int bid = blockIdx.x;
  if (bid < 160) {  // gates: M=1280, N=2048, K=512
    const int rb = (bid >> 4) * 128, cb = (bid & 15) * 128;
    gemm_tile(h16, Wall, 512, rb, cb, sh, [&](int r, int c, float v) {
      v += Wall_b[c] + Uall_b[c] + (float)ux[((size_t)r * 30 + s) * 2048 + c];
      g4[(size_t)r * 2048 + c] = 1.f / (1.f + __expf(-v));
    });
  } else {          // c_s1: M=1280, N=512, K=512
    const int b2 = bid - 160;
    const int rb = (b2 >> 2) * 128, cb = (b2 & 3) * 128;
    gemm_tile(c16, Wd, 512, rb, cb, sh, [&](int r, int c, float v) {
      csl[(size_t)r * 512 + c] = tanhf(v + Wd_b[c]);
    });
  }
}

// TimeLSTM elementwise update (gate order f,i,o,c_tmp; all sigmoid; outs stacks o)
__global__ __launch_bounds__(256) void k_ew(const float* __restrict__ g4, const float* __restrict__ csl,
                                            const float* __restrict__ timef, float* __restrict__ c32,
                                            f16* __restrict__ c16, f16* __restrict__ h16,
                                            f16* __restrict__ outs, int s) {
  const int idx = blockIdx.x * 256 + threadIdx.x;   // < 1280*512
  const int n = idx >> 9, h = idx & 511;
  const int d = n >> 8, b = n & 255;
  const float f = g4[(size_t)n * 2048 + h];
  const float i = g4[(size_t)n * 2048 + 512 + h];
  const float o = g4[(size_t)n * 2048 + 1024 + h];
  const float ct = g4[(size_t)n * 2048 + 1536 + h];
  const float cs = csl[idx];
  const float tv = timef[((size_t)b * 5 + d) * 30 + s];
  float c = c32[idx];
  const float cadj = c - cs + cs * tv;
  c = f * cadj + i * ct;
  const float hh = o * tanhf(c);
  c32[idx] = c;
  c16[idx] = (f16)c;
  h16[idx] = (f16)hh;
  outs[((size_t)n * 30 + s) * 512 + h] = (f16)o;
}

// w1last[d] = A1_W1 @ outs[d, B-1, len-1] + b  (the reference's shared "temp_hn")
__global__ __launch_bounds__(256) void k_w1last(const f16* __restrict__ outs, const int* __restrict__ lens,
                                                const float* __restrict__ W1, const float* __restrict__ W1b,
                                                float* __restrict__ w1l) {
  __shared__ float lastv[512];
  const int d = blockIdx.x;
  const int idx = lens[255 * 5 + d] - 1;
  const size_t row = ((size_t)(d * 256 + 255) * 30 + idx) * 512;
  for (int h = threadIdx.x; h < 512; h += 256) lastv[h] = (float)outs[row + h];
  __syncthreads();
  for (int h = threadIdx.x; h < 512; h += 256) {
    const float* wr = W1 + (size_t)h * 512;
    float p = W1b[h];
    for (int k = 0; k < 512; ++k) p += lastv[k] * wr[k];
    w1l[d * 512 + h] = p;
  }
}

// attn1: score = V.tanh(w1last + t1), mask s<len, softmax over S, weighted sum of outs
__global__ __launch_bounds__(256) void k_attn1(const float* __restrict__ t1, const float* __restrict__ w1l,
                                               const f16* __restrict__ outs, const float* __restrict__ V,
                                               const float* __restrict__ Vb, const int* __restrict__ lens,
                                               float* __restrict__ l1o32, f16* __restrict__ l1o16) {
  __shared__ float ssc[30];
  __shared__ float saw[30];
  const int n = blockIdx.x;
  const int d = n >> 8, b = n & 255;
  const int len = lens[b * 5 + d];
  const int t = threadIdx.x, lane = t & 63, w = t >> 6;
  for (int s = w; s < 30; s += 4) {
    const float* tr = t1 + ((size_t)n * 30 + s) * 512;
    const float* wl = w1l + d * 512;
    float p = 0.f;
#pragma unroll
    for (int j = 0; j < 8; ++j) { int h = lane * 8 + j; p += V[h] * tanhf(tr[h] + wl[h]); }
#pragma unroll
    for (int off = 32; off > 0; off >>= 1) p += __shfl_down(p, off);
    if (lane == 0) ssc[s] = p + Vb[0];
  }
  __syncthreads();
  if (w == 0) {
    const bool valid = (lane < 30) && (lane < len);
    float sc = valid ? ssc[lane] : -INFINITY;
    float mx = sc;
#pragma unroll
    for (int off = 32; off > 0; off >>= 1) mx = fmaxf(mx, __shfl_xor(mx, off));
    float e = valid ? __expf(sc - mx) : 0.f;
    float sm = e;
#pragma unroll
    for (int off = 32; off > 0; off >>= 1) sm += __shfl_xor(sm, off);
    if (lane < 30) saw[lane] = e / sm;
  }
  __syncthreads();
  for (int h = t; h < 512; h += 256) {
    float acc = 0.f;
    for (int s = 0; s < len; ++s) acc += saw[s] * (float)outs[((size_t)n * 30 + s) * 512 + h];
    const size_t o = ((size_t)b * 5 + d) * 512 + h;
    l1o32[o] = acc;
    l1o16[o] = (f16)acc;
  }
}

// lstm2 recurrent GEMM: gpre = xi2[:,t,:] + h2@Whh^T
__global__ __launch_bounds__(256, 2) void k_l2gemm(const f16* __restrict__ h2, const f16* __restrict__ Whh,
                                                   const float* __restrict__ xi2, float* __restrict__ g2, int t) {
  __shared__ f16x8 sh[4096];
  const int rb = blockIdx.y * 128, cb = blockIdx.x * 128;
  gemm_tile(h2, Whh, 512, rb, cb, sh, [&](int r, int c, float v) {
    g2[(size_t)r * 2048 + c] = v + xi2[((size_t)r * 5 + t) * 2048 + c];
  });
}

// lstm2 elementwise (PyTorch gate order i,f,g,o)
__global__ __launch_bounds__(256) void k_ew2(const float* __restrict__ g2, float* __restrict__ c2,
                                             f16* __restrict__ h2, float* __restrict__ l2o32,
                                             f16* __restrict__ l2o16, int t) {
  const int idx = blockIdx.x * 256 + threadIdx.x;   // < 256*512
  const int b = idx >> 9, h = idx & 511;
  const float* g = g2 + (size_t)b * 2048;
  const float ii = sigf(g[h]), ff = sigf(g[512 + h]), gg = tanhf(g[1024 + h]), oo = sigf(g[1536 + h]);
  const float c = ff * c2[idx] + ii * gg;
  const float hh = oo * tanhf(c);
  c2[idx] = c;
  h2[idx] = (f16)hh;
  const size_t o = ((size_t)b * 5 + t) * 512 + h;
  l2o32[o] = hh;
  l2o16[o] = (f16)hh;
}

// attn2 over D=5 days
__global__ __launch_bounds__(256) void k_attn2(const float* __restrict__ u2, const float* __restrict__ v2,
                                               const float* __restrict__ l2o, const float* __restrict__ V2,
                                               const float* __restrict__ V2b, f16* __restrict__ ctx16) {
  __shared__ float ssc[5];
  __shared__ float saw[5];
  const int b = blockIdx.x;
  const int t = threadIdx.x, lane = t & 63, w = t >> 6;
  for (int tt = w; tt < 5; tt += 4) {
    const float* ur = u2 + ((size_t)b * 5 + tt) * 512;
    const float* vr = v2 + (size_t)b * 512;
    float p = 0.f;
#pragma unroll
    for (int j = 0; j < 8; ++j) { int h = lane * 8 + j; p += V2[h] * tanhf(ur[h] + vr[h]); }
#pragma unroll
    for (int off = 32; off > 0; off >>= 1) p += __shfl_down(p, off);
    if (lane == 0) ssc[tt] = p + V2b[0];
  }
  __syncthreads();
  if (w == 0) {
    const bool valid = lane < 5;
    float sc = valid ? ssc[lane] : -INFINITY;
    float mx = sc;
#pragma unroll
    for (int off = 32; off > 0; off >>= 1) mx = fmaxf(mx, __shfl_xor(mx, off));
    float e = valid ? __expf(sc - mx) : 0.f;
    float sm = e;
#pragma unroll
    for (int off = 32; off > 0; off >>= 1) sm += __shfl_xor(sm, off);
    if (valid) saw[lane] = e / sm;
  }
  __syncthreads();
  for (int h = t; h < 512; h += 256) {
    float a = 0.f;
#pragma unroll
    for (int tt = 0; tt < 5; ++tt) a += saw[tt] * l2o[((size_t)b * 5 + tt) * 512 + h];
    ctx16[(size_t)b * 512 + h] = (f16)a;
  }
}

// final: out = h3 @ lin4^T + b4  (256x2, fp32)
__global__ __launch_bounds__(256) void k_final(const float* __restrict__ h3, const float* __restrict__ W4,
                                               const float* __restrict__ b4, float* __restrict__ out) {
  const int idx = blockIdx.x * 256 + threadIdx.x;   // 512
  const int b = idx >> 1, o = idx & 1;
  const float* hr = h3 + b * 256;
  const float* wr = W4 + o * 256;
  float p = b4[o];
  for (int j = 0; j < 256; ++j) p += hr[j] * wr[j];
  out[idx] = p;
}

// ---------------- prep kernels ----------------
// x cast: sentence_feats (B,D,S,E) f32 -> x16 rows m=(d*256+b)*30+s
__global__ __launch_bounds__(192) void k_castx(const float* __restrict__ sf, f16* __restrict__ x16) {
  const int m = blockIdx.x;
  const int d = m / 7680;
  const int r = m - d * 7680;
  const int b = r / 30;
  const int s = r - b * 30;
  const float4 v = ((const float4*)(sf + ((size_t)(b * 5 + d) * 30 + s) * 768))[threadIdx.x];
  f16x4 o = {(f16)v.x, (f16)v.y, (f16)v.z, (f16)v.w};
  ((f16x4*)(x16 + (size_t)m * 768))[threadIdx.x] = o;
}

struct CastArgs {
  const float* src[9];
  f16* dst[9];
  int cnt4[9];
};
__global__ __launch_bounds__(256) void k_castw(CastArgs a) {
  int g = blockIdx.x * 256 + threadIdx.x;
#pragma unroll
  for (int si = 0; si < 9; ++si) {
    if (g < a.cnt4[si]) {
      const float4 v = ((const float4*)a.src[si])[g];
      f16x4 o = {(f16)v.x, (f16)v.y, (f16)v.z, (f16)v.w};
      ((f16x4*)a.dst[si])[g] = o;
      return;
    }
    g -= a.cnt4[si];
  }
}

__global__ __launch_bounds__(256) void k_zero(f16* h16, f16* c16, float* c32, f16* h2, float* c2) {
  const int i = blockIdx.x * 256 + threadIdx.x;
  if (i < 655360) { h16[i] = (f16)0.f; c16[i] = (f16)0.f; c32[i] = 0.f; }
  if (i < 131072) { h2[i] = (f16)0.f; c2[i] = 0.f; }
}

// ---------------- launch ----------------
extern "C" void kernel_launch(void* const* d_in, const int* in_sizes, int n_in,
                              void* d_out, int out_size, void* d_ws, size_t ws_size,
                              hipStream_t stream) {
  const float* sf     = (const float*)d_in[0];
  const float* tf     = (const float*)d_in[1];
  const int*   lens   = (const int*)d_in[2];
  const float* Wd_w   = (const float*)d_in[3];
  const float* Wd_b   = (const float*)d_in[4];
  const float* Wall_w = (const float*)d_in[5];
  const float* Wall_b = (const float*)d_in[6];
  const float* Uall_w = (const float*)d_in[7];
  const float* Uall_b = (const float*)d_in[8];
  const float* A1W1   = (const float*)d_in[9];
  const float* A1W1b  = (const float*)d_in[10];
  const float* A1W2   = (const float*)d_in[11];
  const float* A1W2b  = (const float*)d_in[12];
  const float* A1V    = (const float*)d_in[13];
  const float* A1Vb   = (const float*)d_in[14];
  const float* Wih    = (const float*)d_in[15];
  const float* Whh    = (const float*)d_in[16];
  const float* bih    = (const float*)d_in[17];
  const float* bhh    = (const float*)d_in[18];
  const float* A2W1   = (const float*)d_in[19];
  const float* A2W1b  = (const float*)d_in[20];
  const float* A2W2   = (const float*)d_in[21];
  const float* A2W2b  = (const float*)d_in[22];
  const float* A2V    = (const float*)d_in[23];
  const float* A2Vb   = (const float*)d_in[24];
  const float* L3w    = (const float*)d_in[25];
  const float* L3b    = (const float*)d_in[26];
  const float* L4w    = (const float*)d_in[27];
  const float* L4b    = (const float*)d_in[28];

  if (ws_size < WS_NEED) return;  // zero output will flag this loudly
  char* ws = (char*)d_ws;
  f16*   x16    = (f16*)(ws + OFF_X16);
  f16*   ux16   = (f16*)(ws + OFF_UX);
  float* t1     = (float*)(ws + OFF_UX);   // overlays ux after recurrence
  f16*   outs16 = (f16*)(ws + OFF_OUTS);
  f16*   Wd16   = (f16*)(ws + OFF_WD);
  f16*   Wall16 = (f16*)(ws + OFF_WALL);
  f16*   U16    = (f16*)(ws + OFF_U16);
  f16*   W216   = (f16*)(ws + OFF_W2);
  f16*   Wih16  = (f16*)(ws + OFF_WIH);
  f16*   Whh16  = (f16*)(ws + OFF_WHH);
  f16*   A2W116 = (f16*)(ws + OFF_A2W1);
  f16*   A2W216 = (f16*)(ws + OFF_A2W2);
  f16*   L316   = (f16*)(ws + OFF_L3W);
  f16*   h16    = (f16*)(ws + OFF_H16);
  f16*   c16    = (f16*)(ws + OFF_C16);
  float* c32    = (float*)(ws + OFF_C32);
  float* csl    = (float*)(ws + OFF_CSL);
  float* g4     = (float*)(ws + OFF_G4);
  float* g2     = (float*)(ws + OFF_G4);   // lstm2 reuses g4
  float* w1l    = (float*)(ws + OFF_W1L);
  float* l1o32  = (float*)(ws + OFF_L1O32);
  f16*   l1o16  = (f16*)(ws + OFF_L1O16);
  float* xi2    = (float*)(ws + OFF_XI2);
  float* c2     = (float*)(ws + OFF_C2);
  f16*   h2     = (f16*)(ws + OFF_H2);
  float* l2o32  = (float*)(ws + OFF_L2O32);
  f16*   l2o16  = (f16*)(ws + OFF_L2O16);
  float* u2     = (float*)(ws + OFF_U2);
  float* v2     = (float*)(ws + OFF_V2);
  f16*   ctx16  = (f16*)(ws + OFF_CTX16);
  float* h3     = (float*)(ws + OFF_H3);

  // 1. casts + init
  k_castx<<<38400, 192, 0, stream>>>(sf, x16);
  CastArgs ca;
  ca.src[0] = Wd_w;   ca.dst[0] = Wd16;   ca.cnt4[0] = 262144 / 4;
  ca.src[1] = Wall_w; ca.dst[1] = Wall16; ca.cnt4[1] = 1048576 / 4;
  ca.src[2] = Uall_w; ca.dst[2] = U16;    ca.cnt4[2] = 1572864 / 4;
  ca.src[3] = A1W2;   ca.dst[3] = W216;   ca.cnt4[3] = 262144 / 4;
  ca.src[4] = Wih;    ca.dst[4] = Wih16;  ca.cnt4[4] = 1048576 / 4;
  ca.src[5] = Whh;    ca.dst[5] = Whh16;  ca.cnt4[5] = 1048576 / 4;
  ca.src[6] = A2W1;   ca.dst[6] = A2W116; ca.cnt4[6] = 262144 / 4;
  ca.src[7] = A2W2;   ca.dst[7] = A2W216; ca.cnt4[7] = 262144 / 4;
  ca.src[8] = L3w;    ca.dst[8] = L316;   ca.cnt4[8] = 131072 / 4;
  k_castw<<<5760, 256, 0, stream>>>(ca);
  k_zero<<<2560, 256, 0, stream>>>(h16, c16, c32, h2, c2);

  // 2. ux = x @ Uall^T   (M=38400, N=2048, K=768) -> f16
  k_gemm<0, false, true><<<dim3(16, 300), 256, 0, stream>>>(x16, U16, 768, 2048, nullptr, nullptr, nullptr, ux16);

  // 3. TimeLSTM recurrence, 30 steps
  for (int s = 0; s < 30; ++s) {
    k_step<<<200, 256, 0, stream>>>(h16, c16, Wall16, Wd16, ux16, Wall_b, Uall_b, Wd_b, g4, csl, s);
    k_ew<<<2560, 256, 0, stream>>>(g4, csl, tf, c32, c16, h16, outs16, s);
  }

  // 4. attn1
  k_w1last<<<5, 256, 0, stream>>>(outs16, lens, A1W1, A1W1b, w1l);
  k_gemm<0, true, false><<<dim3(4, 300), 256, 0, stream>>>(outs16, W216, 512, 512, A1W2b, nullptr, t1, nullptr);
  k_attn1<<<1280, 256, 0, stream>>>(t1, w1l, outs16, A1V, A1Vb, lens, l1o32, l1o16);

  // 5. lstm2
  k_gemm<0, true, false><<<dim3(16, 10), 256, 0, stream>>>(l1o16, Wih16, 512, 2048, bih, bhh, xi2, nullptr);
  for (int t = 0; t < 5; ++t) {
    k_l2gemm<<<dim3(16, 2), 256, 0, stream>>>(h2, Whh16, xi2, g2, t);
    k_ew2<<<512, 256, 0, stream>>>(g2, c2, h2, l2o32, l2o16, t);
  }

  // 6. attn2
  k_gemm<0, true, false><<<dim3(4, 10), 256, 0, stream>>>(l2o16, A2W216, 512, 512, A2W2b, nullptr, u2, nullptr);
  k_gemm<0, true, false><<<dim3(4, 2), 256, 0, stream>>>(h2, A2W116, 512, 512, A2W1b, nullptr, v2, nullptr);
  k_attn2<<<256, 256, 0, stream>>>(u2, v2, l2o32, A2V, A2Vb, ctx16);

  // 7. head
  k_gemm<3, true, false><<<dim3(2, 2), 256, 0, stream>>>(ctx16, L316, 512, 256, L3b, nullptr, h3, nullptr);
  k_final<<<2, 256, 0, stream>>>(h3, L4w, L4b, (float*)d_out);
}